// Round 1
// 6594.031 us; speedup vs baseline: 1.2704x; 1.2704x over previous
//
#include <hip/hip_runtime.h>
#include <hip/hip_bf16.h>

// ---------------------------------------------------------------------------
// Strict f64 squared distance matching numpy float64:
//   d = ((dx*dx + dy*dy) + dz*dz), every op individually rounded, no FMA.
// Coords are exact f32 values upcast to f64 (exact).
// ---------------------------------------------------------------------------
__device__ __forceinline__ double dist2d(float x, float y, float z,
                                         double px, double py, double pz) {
    double dx = __dsub_rn((double)x, px);
    double dy = __dsub_rn((double)y, py);
    double dz = __dsub_rn((double)z, pz);
    double a  = __dmul_rn(dx, dx);
    double b  = __dmul_rn(dy, dy);
    double c  = __dmul_rn(dz, dz);
    return __dadd_rn(__dadd_rn(a, b), c);
}

// DPP move; lanes with invalid source keep their own value (bound_ctrl=false).
template <int CTRL>
__device__ __forceinline__ double dpp_f64_keep(double v) {
    long long b = __double_as_longlong(v);
    int lo = (int)(b & 0xFFFFFFFFLL);
    int hi = (int)(((unsigned long long)b) >> 32);
    int lo2 = __builtin_amdgcn_update_dpp(lo, lo, CTRL, 0xF, 0xF, false);
    int hi2 = __builtin_amdgcn_update_dpp(hi, hi, CTRL, 0xF, 0xF, false);
    return __longlong_as_double(((long long)(unsigned)hi2 << 32) | (unsigned)lo2);
}

// After this, lane 63 holds max over all 64 lanes.
__device__ __forceinline__ double wave_max_f64(double v) {
    v = fmax(v, dpp_f64_keep<0x111>(v));  // row_shr:1
    v = fmax(v, dpp_f64_keep<0x112>(v));  // row_shr:2
    v = fmax(v, dpp_f64_keep<0x114>(v));  // row_shr:4
    v = fmax(v, dpp_f64_keep<0x118>(v));  // row_shr:8
    v = fmax(v, dpp_f64_keep<0x142>(v));  // row_bcast:15
    v = fmax(v, dpp_f64_keep<0x143>(v));  // row_bcast:31
    return v;
}

__device__ __forceinline__ double readlane_f64(double v, int l) {
    long long b = __double_as_longlong(v);
    int lo = __builtin_amdgcn_readlane((int)(b & 0xFFFFFFFFLL), l);
    int hi = __builtin_amdgcn_readlane((int)(((unsigned long long)b) >> 32), l);
    return __longlong_as_double(((long long)(unsigned)hi << 32) | (unsigned)lo);
}

__device__ __forceinline__ float readlane_f32(float v, int l) {
    return __int_as_float(__builtin_amdgcn_readlane(__float_as_int(v), l));
}

// ---------------------------------------------------------------------------
// FPS. One block per batch. Point p = j*NT + tid, j < PPT, n_in = PPT*NT.
// f32 coords in registers (exact); f64 running min-dist (bit-matches numpy
// float64); f32 screen thresholds.
//
// ZERO global memory ops inside the serial loop:
//   - each lane tracks its best slot's COORDS (bx,by,bz) alongside (bv,bi)
//     during the rescan; lane0 publishes the wave winner's coords+idx to
//     double-buffered LDS (readlane; readlane ignores exec mask).
//   - ONE barrier/iter; cross-wave DPP reduce of NWAVES partials; winner
//     coords come from a broadcast ds_read_b128 of s_c[par][wl2].
//   - selected indices accumulate in LDS s_hist (npoints<=4096, 16KB) and
//     are dumped coalesced once at the end -> no vmcnt drain at the barrier.
//   - update: branchless per-slot f32 fma screen accumulated into a
//     wave-uniform fmask; ONE branch guards the whole f64-update + rescan
//     block. Screen margin 1.000004 >> 3-ulp fma error, so screened-out
//     slots are provably unchanged; md stays bit-exact.
//
// NOTE: only level-1 FPS is ever run. FPS is *nested*: running FPS on the
// ordered output of a previous FPS provably selects indices 0,1,2,... (the
// pick at step t attains the subset max because it attains the full-set max
// and belongs to the subset; already-selected points have running dist 0;
// argmax tie-break = first occurrence = position t). This holds bit-exactly
// in floating point (identical ops on bit-identical gathered coords), so
// idx2/idx3/idx4 are arange() and levels 2-4 use identity gathers.
// ---------------------------------------------------------------------------
template <int PPT, int NT>
__global__ __launch_bounds__(NT, 2) void fps_kernel(
    const float* __restrict__ pts,  // [B][n_in][stride], xyz at channels 0..2
    int stride, int npoints,
    int* __restrict__ idx_out)      // [B][npoints]
{
    constexpr int NWAVES = NT / 64;
    constexpr int N_IN   = PPT * NT;

    const int batch = blockIdx.x;
    const int tid   = threadIdx.x;
    const int lane  = tid & 63;
    const int wv    = tid >> 6;

    const float* base = pts + (size_t)batch * N_IN * stride;
    int* iout = idx_out + (size_t)batch * npoints;

    __shared__ double s_m[2][NWAVES];
    __shared__ int    s_i[2][NWAVES];
    __shared__ float4 s_c[2][NWAVES];
    __shared__ int    s_hist[4096];   // npoints <= 4096 for all launches

    float  cx[PPT], cy[PPT], cz[PPT];
    double md[PPT];
    float  th[PPT];

#pragma unroll
    for (int j = 0; j < PPT; ++j) {
        int p = j * NT + tid;
        const float* r = base + (size_t)p * stride;
        cx[j] = r[0]; cy[j] = r[1]; cz[j] = r[2];
    }

    // first selected point is index 0
    float q0x = base[0], q0y = base[1], q0z = base[2];
    if (tid == 0) s_hist[0] = 0;

    double bv = -1.0;
    int    bi = 0x7FFFFFFF;
    float  bx = 0.f, by = 0.f, bz = 0.f;
#pragma unroll
    for (int j = 0; j < PPT; ++j) {
        md[j] = dist2d(cx[j], cy[j], cz[j], (double)q0x, (double)q0y, (double)q0z);
        th[j] = __fmul_rn((float)md[j], 1.000004f);
        if (md[j] > bv) { bv = md[j]; bi = j * NT + tid; bx = cx[j]; by = cy[j]; bz = cz[j]; }
    }

    for (int i = 1; i < npoints; ++i) {
        const int par = i & 1;

        // ---- wave-level max (value only, DPP) ----
        double wmax = readlane_f64(wave_max_f64(bv), 63);
        unsigned long long cm = __ballot(bv == wmax);
        int wl;
        if (__popcll(cm) == 1) {
            wl = __ffsll(cm) - 1;
        } else {  // exact tie: pick lane holding the min index (rare)
            int mi = 0x7FFFFFFF, ml = 0;
            unsigned long long t2 = cm;
            while (t2) {
                int l  = __ffsll(t2) - 1;
                int ci = __builtin_amdgcn_readlane(bi, l);
                if (ci < mi) { mi = ci; ml = l; }
                t2 &= t2 - 1;
            }
            wl = ml;
        }
        if (lane == 0) {
            // readlane ignores exec mask of the source lane
            int   wi = __builtin_amdgcn_readlane(bi, wl);
            float wx = readlane_f32(bx, wl);
            float wy = readlane_f32(by, wl);
            float wz = readlane_f32(bz, wl);
            s_m[par][wv] = wmax;
            s_i[par][wv] = wi;
            s_c[par][wv] = make_float4(wx, wy, wz, 0.0f);
        }
        __syncthreads();   // no outstanding vmem in-loop -> vmcnt drain is free

        // ---- cross-wave reduce of NWAVES partials (lanes 0..NWAVES-1) ----
        double pm   = s_m[par][lane & (NWAVES - 1)];
        int    pidx = s_i[par][lane & (NWAVES - 1)];
        double v2 = (lane < NWAVES) ? pm : -1.0;
        v2 = fmax(v2, dpp_f64_keep<0x111>(v2));
        v2 = fmax(v2, dpp_f64_keep<0x112>(v2));
        if (NWAVES == 8) v2 = fmax(v2, dpp_f64_keep<0x114>(v2));
        double gmax = readlane_f64(v2, NWAVES - 1);
        unsigned long long c2 = __ballot((lane < NWAVES) && (pm == gmax));
        int wl2;
        if (__popcll(c2) == 1) {
            wl2 = __ffsll(c2) - 1;
        } else {
            int mi = 0x7FFFFFFF, ml = 0;
            unsigned long long t2 = c2;
            while (t2) {
                int l  = __ffsll(t2) - 1;
                int ci = __builtin_amdgcn_readlane(pidx, l);
                if (ci < mi) { mi = ci; ml = l; }
                t2 &= t2 - 1;
            }
            wl2 = ml;
        }
        int best = __builtin_amdgcn_readlane(pidx, wl2);
        if (tid == 0) s_hist[i] = best;

        // winner coords: broadcast LDS read (wl2 is wave-uniform)
        float4 qc = s_c[par][wl2];
        const float qx = qc.x, qy = qc.y, qz = qc.z;
        const double qx64 = (double)qx, qy64 = (double)qy, qz64 = (double)qz;

        // ---- branchless screen -> wave-uniform fire mask ----
        int fmask = 0;
#pragma unroll
        for (int j = 0; j < PPT; ++j) {
            float dx = cx[j] - qx;
            float dy = cy[j] - qy;
            float dz = cz[j] - qz;
            float d32 = fmaf(dx, dx, fmaf(dy, dy, dz * dz));
            fmask |= (__any(d32 < th[j]) ? (1 << j) : 0);
        }

        if (fmask) {
#pragma unroll
            for (int j = 0; j < PPT; ++j) {
                if (fmask & (1 << j)) {
                    double d = dist2d(cx[j], cy[j], cz[j], qx64, qy64, qz64);
                    md[j] = fmin(md[j], d);   // no-op for unflagged lanes
                    th[j] = __fmul_rn((float)md[j], 1.000004f);
                }
            }
            // rescan only when some md in this wave may have moved
            bv = -1.0; bi = 0x7FFFFFFF;
#pragma unroll
            for (int j = 0; j < PPT; ++j)
                if (md[j] > bv) { bv = md[j]; bi = j * NT + tid; bx = cx[j]; by = cy[j]; bz = cz[j]; }
        }
    }

    // coalesced bulk dump of the selected indices
    __syncthreads();
    for (int i = tid; i < npoints; i += NT) iout[i] = s_hist[i];
}

// ---------------------------------------------------------------------------
// Gather + 2-layer pointwise MLP + xyz/feat concat, one kernel per level.
// IDENT=true: identity gather (FPS nesting property -> idx == arange).
// ---------------------------------------------------------------------------
template <int CIN, int F, bool REPEAT, bool IDENT>
__global__ __launch_bounds__(256) void mlp_kernel(
    const float* __restrict__ pts, int stride, int n_in,
    const int* __restrict__ idx,
    const float* __restrict__ w1, const float* __restrict__ b1,
    const float* __restrict__ w2, const float* __restrict__ b2,
    float* __restrict__ out, int np)
{
    constexpr int P    = 256 / F;
    constexpr int CINS = REPEAT ? (CIN / 2) : CIN;  // stored input channels
    constexpr int LOGF = (F == 16) ? 4 : (F == 32) ? 5 : (F == 64) ? 6 : 7;

    __shared__ float xs[P][CINS];
    __shared__ float h[P][F];

    const int tid = threadIdx.x;
    const int pl  = tid >> LOGF;       // point within block
    const int c   = tid & (F - 1);     // output channel
    const int b   = blockIdx.y;
    const int pid = blockIdx.x * P + pl;

    const int id = IDENT ? pid : idx[(size_t)b * np + pid];
    const float* row = pts + ((size_t)b * n_in + id) * stride;

    if (c < CINS) xs[pl][c] = row[c];
    __syncthreads();

    float acc = b1[c];
#pragma unroll
    for (int k = 0; k < CIN; ++k) {
        const int xk = REPEAT ? (k % 3) : k;
        acc = fmaf(xs[pl][xk], w1[k * F + c], acc);
    }
    h[pl][c] = fmaxf(acc, 0.0f);
    __syncthreads();

    float acc2 = b2[c];
#pragma unroll
    for (int f = 0; f < F; ++f)
        acc2 = fmaf(h[pl][f], w2[f * F + c], acc2);

    float res = (c < 3) ? xs[pl][c] : acc2;
    out[((size_t)b * np + pid) * (size_t)F + c] = res;
}

// ---------------------------------------------------------------------------
// Launch. FPS nesting property: only level-1 FPS is computed; levels 2-4
// select the first np rows of the previous level's output (identity gather).
// ---------------------------------------------------------------------------
extern "C" void kernel_launch(void* const* d_in, const int* in_sizes, int n_in_cnt,
                              void* d_out, int out_size, void* d_ws, size_t ws_size,
                              hipStream_t stream) {
    const float* scene = (const float*)d_in[0];
    const float* w1_1 = (const float*)d_in[1];
    const float* b1_1 = (const float*)d_in[2];
    const float* w2_1 = (const float*)d_in[3];
    const float* b2_1 = (const float*)d_in[4];
    const float* w1_2 = (const float*)d_in[5];
    const float* b1_2 = (const float*)d_in[6];
    const float* w2_2 = (const float*)d_in[7];
    const float* b2_2 = (const float*)d_in[8];
    const float* w1_3 = (const float*)d_in[9];
    const float* b1_3 = (const float*)d_in[10];
    const float* w2_3 = (const float*)d_in[11];
    const float* b2_3 = (const float*)d_in[12];
    const float* w1_4 = (const float*)d_in[13];
    const float* b1_4 = (const float*)d_in[14];
    const float* w2_4 = (const float*)d_in[15];
    const float* b2_4 = (const float*)d_in[16];

    float* out  = (float*)d_out;
    float* out1 = out;                 // [8][4096][16]
    float* out2 = out + 524288;        // [8][2048][32]
    float* out3 = out + 1048576;       // [8][1024][64]
    float* out4 = out + 1572864;       // [8][512][128]

    int* idx1 = (int*)d_ws;            // 8*4096 (only level-1 indices needed)

    const int B = 8;

    // Level 1: N=8192 -> 4096, cin=6 (repeat), F=16
    fps_kernel<16, 512><<<B, 512, 0, stream>>>(scene, 3, 4096, idx1);
    mlp_kernel<6, 16, true, false><<<dim3(256, B), 256, 0, stream>>>(
        scene, 3, 8192, idx1, w1_1, b1_1, w2_1, b2_1, out1, 4096);

    // Level 2: 4096 -> 2048, cin=16, F=32   (identity gather, no FPS)
    mlp_kernel<16, 32, false, true><<<dim3(256, B), 256, 0, stream>>>(
        out1, 16, 4096, nullptr, w1_2, b1_2, w2_2, b2_2, out2, 2048);

    // Level 3: 2048 -> 1024, cin=32, F=64   (identity gather, no FPS)
    mlp_kernel<32, 64, false, true><<<dim3(256, B), 256, 0, stream>>>(
        out2, 32, 2048, nullptr, w1_3, b1_3, w2_3, b2_3, out3, 1024);

    // Level 4: 1024 -> 512, cin=64, F=128   (identity gather, no FPS)
    mlp_kernel<64, 128, false, true><<<dim3(256, B), 256, 0, stream>>>(
        out3, 64, 1024, nullptr, w1_4, b1_4, w2_4, b2_4, out4, 512);
}

// Round 2
// 6056.190 us; speedup vs baseline: 1.3832x; 1.0888x over previous
//
#include <hip/hip_runtime.h>

typedef float f32x2 __attribute__((ext_vector_type(2)));

// ---------------------------------------------------------------------------
// VOP3P packed f32 (2 lanes' worth of f32 math per instruction per lane).
// Same IEEE f32 RN rounding per element as the scalar ops they replace.
// ---------------------------------------------------------------------------
__device__ __forceinline__ f32x2 pk_add(f32x2 a, f32x2 b) {
    f32x2 d; asm("v_pk_add_f32 %0, %1, %2" : "=v"(d) : "v"(a), "v"(b)); return d;
}
__device__ __forceinline__ f32x2 pk_mul(f32x2 a, f32x2 b) {
    f32x2 d; asm("v_pk_mul_f32 %0, %1, %2" : "=v"(d) : "v"(a), "v"(b)); return d;
}
__device__ __forceinline__ f32x2 pk_fma(f32x2 a, f32x2 b, f32x2 c) {
    f32x2 d; asm("v_pk_fma_f32 %0, %1, %2, %3" : "=v"(d) : "v"(a), "v"(b), "v"(c)); return d;
}

// ---------------------------------------------------------------------------
// Strict f64 squared distance matching numpy float64:
//   d = ((dx*dx + dy*dy) + dz*dz), every op individually rounded, no FMA.
// ---------------------------------------------------------------------------
__device__ __forceinline__ double dist2d(float x, float y, float z,
                                         double px, double py, double pz) {
    double dx = __dsub_rn((double)x, px);
    double dy = __dsub_rn((double)y, py);
    double dz = __dsub_rn((double)z, pz);
    double a  = __dmul_rn(dx, dx);
    double b  = __dmul_rn(dy, dy);
    double c  = __dmul_rn(dz, dz);
    return __dadd_rn(__dadd_rn(a, b), c);
}

// DPP move; lanes with invalid source keep their own value (bound_ctrl=false).
template <int CTRL>
__device__ __forceinline__ double dpp_f64_keep(double v) {
    long long b = __double_as_longlong(v);
    int lo = (int)(b & 0xFFFFFFFFLL);
    int hi = (int)(((unsigned long long)b) >> 32);
    int lo2 = __builtin_amdgcn_update_dpp(lo, lo, CTRL, 0xF, 0xF, false);
    int hi2 = __builtin_amdgcn_update_dpp(hi, hi, CTRL, 0xF, 0xF, false);
    return __longlong_as_double(((long long)(unsigned)hi2 << 32) | (unsigned)lo2);
}

// After this, lane 63 holds max over all 64 lanes.
__device__ __forceinline__ double wave_max_f64(double v) {
    v = fmax(v, dpp_f64_keep<0x111>(v));  // row_shr:1
    v = fmax(v, dpp_f64_keep<0x112>(v));  // row_shr:2
    v = fmax(v, dpp_f64_keep<0x114>(v));  // row_shr:4
    v = fmax(v, dpp_f64_keep<0x118>(v));  // row_shr:8
    v = fmax(v, dpp_f64_keep<0x142>(v));  // row_bcast:15
    v = fmax(v, dpp_f64_keep<0x143>(v));  // row_bcast:31
    return v;
}

__device__ __forceinline__ double readlane_f64(double v, int l) {
    long long b = __double_as_longlong(v);
    int lo = __builtin_amdgcn_readlane((int)(b & 0xFFFFFFFFLL), l);
    int hi = __builtin_amdgcn_readlane((int)(((unsigned long long)b) >> 32), l);
    return __longlong_as_double(((long long)(unsigned)hi << 32) | (unsigned)lo);
}

__device__ __forceinline__ float readlane_f32(float v, int l) {
    return __int_as_float(__builtin_amdgcn_readlane(__float_as_int(v), l));
}

// ---------------------------------------------------------------------------
// FPS. One block per batch. Point p = j*NT + tid, j < PPT, n_in = PPT*NT.
// NT=1024 (16 waves, 4/SIMD): halves per-wave screen/rescan chains vs NT=512
// and doubles waves/SIMD for latency hiding; per-SIMD issue count constant.
//
// f32 coords in registers (exact, f32x2-packed); f64 running min-dist
// (bit-matches numpy float64); f32 packed screen.
//   - ZERO global memory ops in the serial loop (LDS partials + LDS history).
//   - each lane tracks its best slot's coords alongside (bv,bi); lane0
//     publishes wave winner (value,idx,coords) via readlane to double-
//     buffered LDS; ONE barrier/iter; redundant cross-wave DPP reduce.
//   - screen: v_pk_* packed f32 per slot-pair, identical per-element f32
//     rounding to the scalar form, margin 1.000004 >> 3-ulp fma error, so
//     screened-out slots are provably unchanged; md stays bit-exact.
//
// Only level-1 FPS runs. FPS is nested: FPS on the ordered output of a
// previous FPS selects indices 0,1,2,... bit-exactly (subset-max argument;
// already-selected points have running dist 0; argmax tie-break = first
// occurrence = position t). So idx2/3/4 are arange() -> identity gathers.
// ---------------------------------------------------------------------------
template <int PPT, int NT>
__global__ __launch_bounds__(NT, 4) void fps_kernel(
    const float* __restrict__ pts,  // [B][n_in][stride], xyz at channels 0..2
    int stride, int npoints,
    int* __restrict__ idx_out)      // [B][npoints]
{
    constexpr int NWAVES = NT / 64;
    constexpr int N_IN   = PPT * NT;
    constexpr int NPAIR  = PPT / 2;

    const int batch = blockIdx.x;
    const int tid   = threadIdx.x;
    const int lane  = tid & 63;
    const int wv    = tid >> 6;

    const float* base = pts + (size_t)batch * N_IN * stride;
    int* iout = idx_out + (size_t)batch * npoints;

    __shared__ double s_m[2][NWAVES];
    __shared__ int    s_i[2][NWAVES];
    __shared__ float4 s_c[2][NWAVES];
    __shared__ int    s_hist[4096];   // npoints <= 4096

    f32x2  pcx[NPAIR], pcy[NPAIR], pcz[NPAIR];
    double md[PPT];
    float  th[PPT];

#pragma unroll
    for (int k = 0; k < NPAIR; ++k) {
        int p0 = (2 * k) * NT + tid;
        int p1 = (2 * k + 1) * NT + tid;
        const float* r0 = base + (size_t)p0 * stride;
        const float* r1 = base + (size_t)p1 * stride;
        pcx[k] = f32x2{r0[0], r1[0]};
        pcy[k] = f32x2{r0[1], r1[1]};
        pcz[k] = f32x2{r0[2], r1[2]};
    }

    // first selected point is index 0
    float q0x = base[0], q0y = base[1], q0z = base[2];
    if (tid == 0) s_hist[0] = 0;

    double bv = -1.0;
    int    bi = 0x7FFFFFFF;
    float  bx = 0.f, by = 0.f, bz = 0.f;
#pragma unroll
    for (int j = 0; j < PPT; ++j) {
        float x = pcx[j / 2][j & 1], y = pcy[j / 2][j & 1], z = pcz[j / 2][j & 1];
        md[j] = dist2d(x, y, z, (double)q0x, (double)q0y, (double)q0z);
        th[j] = __fmul_rn((float)md[j], 1.000004f);
        if (md[j] > bv) { bv = md[j]; bi = j * NT + tid; bx = x; by = y; bz = z; }
    }

    for (int i = 1; i < npoints; ++i) {
        const int par = i & 1;

        // ---- wave-level max (value only, DPP) ----
        double wmax = readlane_f64(wave_max_f64(bv), 63);
        unsigned long long cm = __ballot(bv == wmax);
        int wl;
        if (__popcll(cm) == 1) {
            wl = __ffsll(cm) - 1;
        } else {  // exact tie: pick lane holding the min index (rare)
            int mi = 0x7FFFFFFF, ml = 0;
            unsigned long long t2 = cm;
            while (t2) {
                int l  = __ffsll(t2) - 1;
                int ci = __builtin_amdgcn_readlane(bi, l);
                if (ci < mi) { mi = ci; ml = l; }
                t2 &= t2 - 1;
            }
            wl = ml;
        }
        if (lane == 0) {
            // readlane ignores exec mask of the source lane
            int   wi = __builtin_amdgcn_readlane(bi, wl);
            float wx = readlane_f32(bx, wl);
            float wy = readlane_f32(by, wl);
            float wz = readlane_f32(bz, wl);
            s_m[par][wv] = wmax;
            s_i[par][wv] = wi;
            s_c[par][wv] = make_float4(wx, wy, wz, 0.0f);
        }
        __syncthreads();   // no outstanding vmem in-loop -> vmcnt drain is free

        // ---- cross-wave reduce of NWAVES partials (lanes 0..NWAVES-1) ----
        double pm   = s_m[par][lane & (NWAVES - 1)];
        int    pidx = s_i[par][lane & (NWAVES - 1)];
        double v2 = (lane < NWAVES) ? pm : -1.0;
        v2 = fmax(v2, dpp_f64_keep<0x111>(v2));
        v2 = fmax(v2, dpp_f64_keep<0x112>(v2));
        if (NWAVES >= 8)  v2 = fmax(v2, dpp_f64_keep<0x114>(v2));
        if (NWAVES >= 16) v2 = fmax(v2, dpp_f64_keep<0x118>(v2));
        double gmax = readlane_f64(v2, NWAVES - 1);
        unsigned long long c2 = __ballot((lane < NWAVES) && (pm == gmax));
        int wl2;
        if (__popcll(c2) == 1) {
            wl2 = __ffsll(c2) - 1;
        } else {
            int mi = 0x7FFFFFFF, ml = 0;
            unsigned long long t2 = c2;
            while (t2) {
                int l  = __ffsll(t2) - 1;
                int ci = __builtin_amdgcn_readlane(pidx, l);
                if (ci < mi) { mi = ci; ml = l; }
                t2 &= t2 - 1;
            }
            wl2 = ml;
        }
        int best = __builtin_amdgcn_readlane(pidx, wl2);
        if (tid == 0) s_hist[i] = best;

        // winner coords: broadcast LDS read (wl2 is wave-uniform)
        float4 qc = s_c[par][wl2];
        const float qx = qc.x, qy = qc.y, qz = qc.z;
        const double qx64 = (double)qx, qy64 = (double)qy, qz64 = (double)qz;

        // ---- packed branchless screen -> wave-uniform fire mask ----
        const f32x2 nqx = {-qx, -qx}, nqy = {-qy, -qy}, nqz = {-qz, -qz};
        int fmask = 0;
#pragma unroll
        for (int k = 0; k < NPAIR; ++k) {
            f32x2 dx = pk_add(pcx[k], nqx);
            f32x2 dy = pk_add(pcy[k], nqy);
            f32x2 dz = pk_add(pcz[k], nqz);
            f32x2 d  = pk_fma(dx, dx, pk_fma(dy, dy, pk_mul(dz, dz)));
            fmask |= (__any(d.x < th[2 * k])     ? (1 << (2 * k))     : 0);
            fmask |= (__any(d.y < th[2 * k + 1]) ? (1 << (2 * k + 1)) : 0);
        }

        if (fmask) {
#pragma unroll
            for (int j = 0; j < PPT; ++j) {
                if (fmask & (1 << j)) {
                    float x = pcx[j / 2][j & 1], y = pcy[j / 2][j & 1], z = pcz[j / 2][j & 1];
                    double d = dist2d(x, y, z, qx64, qy64, qz64);
                    md[j] = fmin(md[j], d);   // no-op for unflagged lanes
                    th[j] = __fmul_rn((float)md[j], 1.000004f);
                }
            }
            // rescan only when some md in this wave may have moved
            bv = -1.0; bi = 0x7FFFFFFF;
#pragma unroll
            for (int j = 0; j < PPT; ++j) {
                if (md[j] > bv) {
                    bv = md[j]; bi = j * NT + tid;
                    bx = pcx[j / 2][j & 1]; by = pcy[j / 2][j & 1]; bz = pcz[j / 2][j & 1];
                }
            }
        }
    }

    // coalesced bulk dump of the selected indices
    __syncthreads();
    for (int i = tid; i < npoints; i += NT) iout[i] = s_hist[i];
}

// ---------------------------------------------------------------------------
// Gather + 2-layer pointwise MLP + xyz/feat concat, one kernel per level.
// IDENT=true: identity gather (FPS nesting property -> idx == arange).
// ---------------------------------------------------------------------------
template <int CIN, int F, bool REPEAT, bool IDENT>
__global__ __launch_bounds__(256) void mlp_kernel(
    const float* __restrict__ pts, int stride, int n_in,
    const int* __restrict__ idx,
    const float* __restrict__ w1, const float* __restrict__ b1,
    const float* __restrict__ w2, const float* __restrict__ b2,
    float* __restrict__ out, int np)
{
    constexpr int P    = 256 / F;
    constexpr int CINS = REPEAT ? (CIN / 2) : CIN;  // stored input channels
    constexpr int LOGF = (F == 16) ? 4 : (F == 32) ? 5 : (F == 64) ? 6 : 7;

    __shared__ float xs[P][CINS];
    __shared__ float h[P][F];

    const int tid = threadIdx.x;
    const int pl  = tid >> LOGF;       // point within block
    const int c   = tid & (F - 1);     // output channel
    const int b   = blockIdx.y;
    const int pid = blockIdx.x * P + pl;

    const int id = IDENT ? pid : idx[(size_t)b * np + pid];
    const float* row = pts + ((size_t)b * n_in + id) * stride;

    if (c < CINS) xs[pl][c] = row[c];
    __syncthreads();

    float acc = b1[c];
#pragma unroll
    for (int k = 0; k < CIN; ++k) {
        const int xk = REPEAT ? (k % 3) : k;
        acc = fmaf(xs[pl][xk], w1[k * F + c], acc);
    }
    h[pl][c] = fmaxf(acc, 0.0f);
    __syncthreads();

    float acc2 = b2[c];
#pragma unroll
    for (int f = 0; f < F; ++f)
        acc2 = fmaf(h[pl][f], w2[f * F + c], acc2);

    float res = (c < 3) ? xs[pl][c] : acc2;
    out[((size_t)b * np + pid) * (size_t)F + c] = res;
}

// ---------------------------------------------------------------------------
// Launch. Only level-1 FPS is computed; levels 2-4 are identity gathers.
// ---------------------------------------------------------------------------
extern "C" void kernel_launch(void* const* d_in, const int* in_sizes, int n_in_cnt,
                              void* d_out, int out_size, void* d_ws, size_t ws_size,
                              hipStream_t stream) {
    const float* scene = (const float*)d_in[0];
    const float* w1_1 = (const float*)d_in[1];
    const float* b1_1 = (const float*)d_in[2];
    const float* w2_1 = (const float*)d_in[3];
    const float* b2_1 = (const float*)d_in[4];
    const float* w1_2 = (const float*)d_in[5];
    const float* b1_2 = (const float*)d_in[6];
    const float* w2_2 = (const float*)d_in[7];
    const float* b2_2 = (const float*)d_in[8];
    const float* w1_3 = (const float*)d_in[9];
    const float* b1_3 = (const float*)d_in[10];
    const float* w2_3 = (const float*)d_in[11];
    const float* b2_3 = (const float*)d_in[12];
    const float* w1_4 = (const float*)d_in[13];
    const float* b1_4 = (const float*)d_in[14];
    const float* w2_4 = (const float*)d_in[15];
    const float* b2_4 = (const float*)d_in[16];

    float* out  = (float*)d_out;
    float* out1 = out;                 // [8][4096][16]
    float* out2 = out + 524288;        // [8][2048][32]
    float* out3 = out + 1048576;       // [8][1024][64]
    float* out4 = out + 1572864;       // [8][512][128]

    int* idx1 = (int*)d_ws;            // 8*4096 (only level-1 indices needed)

    const int B = 8;

    // Level 1: N=8192 -> 4096, cin=6 (repeat), F=16
    fps_kernel<8, 1024><<<B, 1024, 0, stream>>>(scene, 3, 4096, idx1);
    mlp_kernel<6, 16, true, false><<<dim3(256, B), 256, 0, stream>>>(
        scene, 3, 8192, idx1, w1_1, b1_1, w2_1, b2_1, out1, 4096);

    // Level 2: 4096 -> 2048, cin=16, F=32   (identity gather, no FPS)
    mlp_kernel<16, 32, false, true><<<dim3(256, B), 256, 0, stream>>>(
        out1, 16, 4096, nullptr, w1_2, b1_2, w2_2, b2_2, out2, 2048);

    // Level 3: 2048 -> 1024, cin=32, F=64   (identity gather, no FPS)
    mlp_kernel<32, 64, false, true><<<dim3(256, B), 256, 0, stream>>>(
        out2, 32, 2048, nullptr, w1_3, b1_3, w2_3, b2_3, out3, 1024);

    // Level 4: 1024 -> 512, cin=64, F=128   (identity gather, no FPS)
    mlp_kernel<64, 128, false, true><<<dim3(256, B), 256, 0, stream>>>(
        out3, 64, 1024, nullptr, w1_4, b1_4, w2_4, b2_4, out4, 512);
}

// Round 4
// 5094.712 us; speedup vs baseline: 1.6442x; 1.1887x over previous
//
#include <hip/hip_runtime.h>

typedef float f32x2 __attribute__((ext_vector_type(2)));

// ---------------------------------------------------------------------------
// VOP3P packed f32 (2 f32 ops per instruction per lane). Same IEEE f32 RN
// rounding per element as the scalar ops they replace.
// ---------------------------------------------------------------------------
__device__ __forceinline__ f32x2 pk_add(f32x2 a, f32x2 b) {
    f32x2 d; asm("v_pk_add_f32 %0, %1, %2" : "=v"(d) : "v"(a), "v"(b)); return d;
}
__device__ __forceinline__ f32x2 pk_mul(f32x2 a, f32x2 b) {
    f32x2 d; asm("v_pk_mul_f32 %0, %1, %2" : "=v"(d) : "v"(a), "v"(b)); return d;
}
__device__ __forceinline__ f32x2 pk_fma(f32x2 a, f32x2 b, f32x2 c) {
    f32x2 d; asm("v_pk_fma_f32 %0, %1, %2, %3" : "=v"(d) : "v"(a), "v"(b), "v"(c)); return d;
}

// ---------------------------------------------------------------------------
// Strict f64 squared distance matching numpy float64:
//   d = ((dx*dx + dy*dy) + dz*dz), every op individually rounded, no FMA.
// ---------------------------------------------------------------------------
__device__ __forceinline__ double dist2d(float x, float y, float z,
                                         double px, double py, double pz) {
    double dx = __dsub_rn((double)x, px);
    double dy = __dsub_rn((double)y, py);
    double dz = __dsub_rn((double)z, pz);
    double a  = __dmul_rn(dx, dx);
    double b  = __dmul_rn(dy, dy);
    double c  = __dmul_rn(dz, dz);
    return __dadd_rn(__dadd_rn(a, b), c);
}

// DPP move; lanes with invalid source keep their own value (bound_ctrl=false).
template <int CTRL>
__device__ __forceinline__ unsigned dpp_u32_keep(unsigned v) {
    return (unsigned)__builtin_amdgcn_update_dpp((int)v, (int)v, CTRL, 0xF, 0xF, false);
}

// After this, lane 63 holds umax over all 64 lanes.
__device__ __forceinline__ unsigned wave_umax64(unsigned v) {
    v = max(v, dpp_u32_keep<0x111>(v));  // row_shr:1
    v = max(v, dpp_u32_keep<0x112>(v));  // row_shr:2
    v = max(v, dpp_u32_keep<0x114>(v));  // row_shr:4
    v = max(v, dpp_u32_keep<0x118>(v));  // row_shr:8
    v = max(v, dpp_u32_keep<0x142>(v));  // row_bcast:15
    v = max(v, dpp_u32_keep<0x143>(v));  // row_bcast:31
    return v;
}

__device__ __forceinline__ float readlane_f32(float v, int l) {
    return __int_as_float(__builtin_amdgcn_readlane(__float_as_int(v), l));
}

// ---------------------------------------------------------------------------
// FPS. One block per batch. Point p = j*NT + tid, j < PPT, n_in = PPT*NT.
//
// Exactness: md is f64, bit-matching numpy float64 (dist2d). md >= 0 always,
// and for positive IEEE doubles, value order == integer order of (hi32, lo32).
// All max/argmax machinery therefore runs on u32 hi-words (v_max_u32 DPP);
// exact hi-ties fall to a rare readlane slow path resolving (lo desc, idx asc).
// argmax tie-break = global min index (numpy argmax), via keep-first in-lane
// scans + explicit min-index resolution across lanes/waves.
//
// Issue-count optimizations (the loop is VALU-issue bound on 8 CUs):
//   - cached wave winner: the 64-lane DPP reduce + ballot + readlane extract
//     runs ONLY after a rescan (reduce_winner); steady-state phase 1 is just
//     two masked LDS writes, themselves skipped when the parity buffer is
//     already current (pub0/pub1 flags). Safe because the selected point
//     always fires its own wave's rescan (its own slot takes d=0 < md with
//     bj==j), so a stale cached winner is impossible.
//   - rescan-skip: updates only DECREASE md; keep-first invariant => all
//     j < bj have md[j] < bv strictly, so no new smaller-index tie can form.
//     The lane state is stale iff slot bj itself took d < old. Gate the whole
//     rescan+reduce on __any((j==bj) && (d<old)).
//   - phase 2: lane l<NWAVES loads partial l's {hi,idx} AND {coords,lo}
//     together; winner coords come from readlanes, not a dependent LDS read.
//   - screen: v_pk_* packed f32, per-element rounding identical to scalar;
//     margin 1.000004 >> 3-ulp fma error => screened-out slots provably
//     unchanged; md stays bit-exact.
//   - ZERO global memory ops in the serial loop (LDS history, bulk dump).
//
// Hang/poison safety: all barriers are top-level with uniform trip count;
// tie slow-path loops iterate a strictly-shrinking ballot mask (<=64 iters);
// all in-loop indexing is LDS with indices bounded by construction; 'best'
// is never used as a memory offset, only stored.
//
// Only level-1 FPS runs. FPS is nested: FPS on the ordered output of a
// previous FPS selects indices 0,1,2,... bit-exactly (subset-max argument;
// selected points have running dist 0; argmax tie-break = first occurrence).
// So idx2/3/4 are arange() -> identity gathers in the MLP levels.
// ---------------------------------------------------------------------------
template <int PPT, int NT>
__global__ __launch_bounds__(NT, 4) void fps_kernel(
    const float* __restrict__ pts,  // [B][n_in][stride], xyz at channels 0..2
    int stride, int npoints,
    int* __restrict__ idx_out)      // [B][npoints]
{
    constexpr int NWAVES = NT / 64;
    constexpr int N_IN   = PPT * NT;
    constexpr int NPAIR  = PPT / 2;
    constexpr int LOGNT  = (NT == 1024) ? 10 : (NT == 512) ? 9 : 8;

    const int batch = blockIdx.x;
    const int tid   = threadIdx.x;
    const int lane  = tid & 63;
    const int wv    = tid >> 6;

    const float* base = pts + (size_t)batch * N_IN * stride;
    int* iout = idx_out + (size_t)batch * npoints;

    __shared__ uint2  s_pk[2][NWAVES];   // {hi32 of winner value, winner idx}
    __shared__ float4 s_c[2][NWAVES];    // {x, y, z, lo32-as-float}
    __shared__ int    s_hist[4096];      // npoints <= 4096

    f32x2  pcx[NPAIR], pcy[NPAIR], pcz[NPAIR];
    double md[PPT];
    float  th[PPT];

#pragma unroll
    for (int k = 0; k < NPAIR; ++k) {
        int p0 = (2 * k) * NT + tid;
        int p1 = (2 * k + 1) * NT + tid;
        const float* r0 = base + (size_t)p0 * stride;
        const float* r1 = base + (size_t)p1 * stride;
        pcx[k] = f32x2{r0[0], r1[0]};
        pcy[k] = f32x2{r0[1], r1[1]};
        pcz[k] = f32x2{r0[2], r1[2]};
    }

    // first selected point is index 0
    float q0x = base[0], q0y = base[1], q0z = base[2];
    if (tid == 0) s_hist[0] = 0;

    // per-lane argmax state: value (f64), slot, coords. keep-first scan.
    double bv = -1.0;
    int    bj = 0;
    float  bx = 0.f, by = 0.f, bz = 0.f;
#pragma unroll
    for (int j = 0; j < PPT; ++j) {
        float x = pcx[j / 2][j & 1], y = pcy[j / 2][j & 1], z = pcz[j / 2][j & 1];
        md[j] = dist2d(x, y, z, (double)q0x, (double)q0y, (double)q0z);
        th[j] = __fmul_rn((float)md[j], 1.000004f);
        if (md[j] > bv) { bv = md[j]; bj = j; bx = x; by = y; bz = z; }
    }

    // cached wave winner (wave-uniform after reduce_winner)
    unsigned w_hi = 0, w_lo = 0;
    int      w_i  = 0;
    float    w_x = 0.f, w_y = 0.f, w_z = 0.f;
    bool pub0 = false, pub1 = false;

    auto reduce_winner = [&]() {
        unsigned hi = (unsigned)__double2hiint(bv);
        unsigned lo = (unsigned)__double2loint(bv);
        int      bi = (bj << LOGNT) + tid;
        unsigned maxhi = (unsigned)__builtin_amdgcn_readlane((int)wave_umax64(hi), 63);
        unsigned long long cm = __ballot(hi == maxhi);
        int wl;
        if (__popcll(cm) == 1) {
            wl = __ffsll(cm) - 1;
        } else {  // exact hi tie: resolve (lo desc, idx asc). rare.
            unsigned bl = 0; int bidx = 0x7FFFFFFF; int ml = -1;
            unsigned long long t2 = cm;
            while (t2) {
                int l = __ffsll(t2) - 1;
                unsigned lol = (unsigned)__builtin_amdgcn_readlane((int)lo, l);
                int      il  = __builtin_amdgcn_readlane(bi, l);
                if (ml < 0 || lol > bl || (lol == bl && il < bidx)) {
                    bl = lol; bidx = il; ml = l;
                }
                t2 &= t2 - 1;
            }
            wl = ml;
        }
        w_hi = maxhi;
        w_lo = (unsigned)__builtin_amdgcn_readlane((int)lo, wl);
        w_i  = __builtin_amdgcn_readlane(bi, wl);
        w_x  = readlane_f32(bx, wl);
        w_y  = readlane_f32(by, wl);
        w_z  = readlane_f32(bz, wl);
        pub0 = false; pub1 = false;
    };
    reduce_winner();

    for (int i = 1; i < npoints; ++i) {
        const int par = i & 1;

        // ---- phase 1: publish cached winner (skip if buffer current) ----
        bool pub = par ? pub1 : pub0;
        if (!pub) {
            if (lane == 0) {
                s_pk[par][wv] = make_uint2(w_hi, (unsigned)w_i);
                s_c[par][wv]  = make_float4(w_x, w_y, w_z, __uint_as_float(w_lo));
            }
            if (par) pub1 = true; else pub0 = true;
        }
        __syncthreads();   // no outstanding vmem in-loop -> vmcnt drain free

        // ---- phase 2: reduce NWAVES partials (redundant per wave) ----
        const int sl = lane & (NWAVES - 1);
        uint2  pk = s_pk[par][sl];
        float4 pc = s_c[par][sl];
        unsigned v2 = (lane < NWAVES) ? pk.x : 0u;
        v2 = max(v2, dpp_u32_keep<0x111>(v2));
        v2 = max(v2, dpp_u32_keep<0x112>(v2));
        if constexpr (NWAVES >= 8)  v2 = max(v2, dpp_u32_keep<0x114>(v2));
        if constexpr (NWAVES >= 16) v2 = max(v2, dpp_u32_keep<0x118>(v2));
        unsigned ghi = (unsigned)__builtin_amdgcn_readlane((int)v2, NWAVES - 1);
        unsigned long long c2 = __ballot((lane < NWAVES) && (pk.x == ghi));
        int wl2;
        if (__popcll(c2) == 1) {
            wl2 = __ffsll(c2) - 1;
        } else {  // exact hi tie across waves: (lo desc, idx asc). rare.
            unsigned bl = 0; int bidx = 0x7FFFFFFF; int ml = -1;
            unsigned long long t2 = c2;
            while (t2) {
                int l = __ffsll(t2) - 1;
                unsigned lol = (unsigned)__builtin_amdgcn_readlane(__float_as_int(pc.w), l);
                int      il  = __builtin_amdgcn_readlane((int)pk.y, l);
                if (ml < 0 || lol > bl || (lol == bl && il < bidx)) {
                    bl = lol; bidx = il; ml = l;
                }
                t2 &= t2 - 1;
            }
            wl2 = ml;
        }
        int best = __builtin_amdgcn_readlane((int)pk.y, wl2);
        if (tid == 0) s_hist[i] = best;

        // winner coords via readlane (no dependent LDS read)
        const float qx = readlane_f32(pc.x, wl2);
        const float qy = readlane_f32(pc.y, wl2);
        const float qz = readlane_f32(pc.z, wl2);
        const double qx64 = (double)qx, qy64 = (double)qy, qz64 = (double)qz;

        // ---- packed branchless screen -> wave-uniform fire mask ----
        const f32x2 nqx = {-qx, -qx}, nqy = {-qy, -qy}, nqz = {-qz, -qz};
        int fmask = 0;
#pragma unroll
        for (int k = 0; k < NPAIR; ++k) {
            f32x2 dx = pk_add(pcx[k], nqx);
            f32x2 dy = pk_add(pcy[k], nqy);
            f32x2 dz = pk_add(pcz[k], nqz);
            f32x2 d  = pk_fma(dx, dx, pk_fma(dy, dy, pk_mul(dz, dz)));
            fmask |= (__any(d.x < th[2 * k])     ? (1 << (2 * k))     : 0);
            fmask |= (__any(d.y < th[2 * k + 1]) ? (1 << (2 * k + 1)) : 0);
        }

        if (fmask) {
            bool need = false;
#pragma unroll
            for (int j = 0; j < PPT; ++j) {
                if (fmask & (1 << j)) {
                    float x = pcx[j / 2][j & 1], y = pcy[j / 2][j & 1], z = pcz[j / 2][j & 1];
                    double d   = dist2d(x, y, z, qx64, qy64, qz64);
                    double old = md[j];
                    // stale iff the best slot itself decreased (see proof above)
                    need = need | ((bj == j) & (d < old));
                    md[j] = fmin(old, d);
                    th[j] = __fmul_rn((float)md[j], 1.000004f);
                }
            }
            if (__any(need)) {
                bv = -1.0; bj = 0;
#pragma unroll
                for (int j = 0; j < PPT; ++j) {
                    if (md[j] > bv) {
                        bv = md[j]; bj = j;
                        bx = pcx[j / 2][j & 1]; by = pcy[j / 2][j & 1]; bz = pcz[j / 2][j & 1];
                    }
                }
                reduce_winner();
            }
        }
    }

    // coalesced bulk dump of the selected indices
    __syncthreads();
    for (int i = tid; i < npoints; i += NT) iout[i] = s_hist[i];
}

// ---------------------------------------------------------------------------
// Gather + 2-layer pointwise MLP + xyz/feat concat, one kernel per level.
// IDENT=true: identity gather (FPS nesting property -> idx == arange).
// ---------------------------------------------------------------------------
template <int CIN, int F, bool REPEAT, bool IDENT>
__global__ __launch_bounds__(256) void mlp_kernel(
    const float* __restrict__ pts, int stride, int n_in,
    const int* __restrict__ idx,
    const float* __restrict__ w1, const float* __restrict__ b1,
    const float* __restrict__ w2, const float* __restrict__ b2,
    float* __restrict__ out, int np)
{
    constexpr int P    = 256 / F;
    constexpr int CINS = REPEAT ? (CIN / 2) : CIN;  // stored input channels
    constexpr int LOGF = (F == 16) ? 4 : (F == 32) ? 5 : (F == 64) ? 6 : 7;

    __shared__ float xs[P][CINS];
    __shared__ float h[P][F];

    const int tid = threadIdx.x;
    const int pl  = tid >> LOGF;       // point within block
    const int c   = tid & (F - 1);     // output channel
    const int b   = blockIdx.y;
    const int pid = blockIdx.x * P + pl;

    const int id = IDENT ? pid : idx[(size_t)b * np + pid];
    const float* row = pts + ((size_t)b * n_in + id) * stride;

    if (c < CINS) xs[pl][c] = row[c];
    __syncthreads();

    float acc = b1[c];
#pragma unroll
    for (int k = 0; k < CIN; ++k) {
        const int xk = REPEAT ? (k % 3) : k;
        acc = fmaf(xs[pl][xk], w1[k * F + c], acc);
    }
    h[pl][c] = fmaxf(acc, 0.0f);
    __syncthreads();

    float acc2 = b2[c];
#pragma unroll
    for (int f = 0; f < F; ++f)
        acc2 = fmaf(h[pl][f], w2[f * F + c], acc2);

    float res = (c < 3) ? xs[pl][c] : acc2;
    out[((size_t)b * np + pid) * (size_t)F + c] = res;
}

// ---------------------------------------------------------------------------
// Launch. Only level-1 FPS is computed; levels 2-4 are identity gathers.
// ---------------------------------------------------------------------------
extern "C" void kernel_launch(void* const* d_in, const int* in_sizes, int n_in_cnt,
                              void* d_out, int out_size, void* d_ws, size_t ws_size,
                              hipStream_t stream) {
    const float* scene = (const float*)d_in[0];
    const float* w1_1 = (const float*)d_in[1];
    const float* b1_1 = (const float*)d_in[2];
    const float* w2_1 = (const float*)d_in[3];
    const float* b2_1 = (const float*)d_in[4];
    const float* w1_2 = (const float*)d_in[5];
    const float* b1_2 = (const float*)d_in[6];
    const float* w2_2 = (const float*)d_in[7];
    const float* b2_2 = (const float*)d_in[8];
    const float* w1_3 = (const float*)d_in[9];
    const float* b1_3 = (const float*)d_in[10];
    const float* w2_3 = (const float*)d_in[11];
    const float* b2_3 = (const float*)d_in[12];
    const float* w1_4 = (const float*)d_in[13];
    const float* b1_4 = (const float*)d_in[14];
    const float* w2_4 = (const float*)d_in[15];
    const float* b2_4 = (const float*)d_in[16];

    float* out  = (float*)d_out;
    float* out1 = out;                 // [8][4096][16]
    float* out2 = out + 524288;        // [8][2048][32]
    float* out3 = out + 1048576;       // [8][1024][64]
    float* out4 = out + 1572864;       // [8][512][128]

    int* idx1 = (int*)d_ws;            // 8*4096 (only level-1 indices needed)

    const int B = 8;

    // Level 1: N=8192 -> 4096, cin=6 (repeat), F=16
    fps_kernel<8, 1024><<<B, 1024, 0, stream>>>(scene, 3, 4096, idx1);
    mlp_kernel<6, 16, true, false><<<dim3(256, B), 256, 0, stream>>>(
        scene, 3, 8192, idx1, w1_1, b1_1, w2_1, b2_1, out1, 4096);

    // Level 2: 4096 -> 2048, cin=16, F=32   (identity gather, no FPS)
    mlp_kernel<16, 32, false, true><<<dim3(256, B), 256, 0, stream>>>(
        out1, 16, 4096, nullptr, w1_2, b1_2, w2_2, b2_2, out2, 2048);

    // Level 3: 2048 -> 1024, cin=32, F=64   (identity gather, no FPS)
    mlp_kernel<32, 64, false, true><<<dim3(256, B), 256, 0, stream>>>(
        out2, 32, 2048, nullptr, w1_3, b1_3, w2_3, b2_3, out3, 1024);

    // Level 4: 1024 -> 512, cin=64, F=128   (identity gather, no FPS)
    mlp_kernel<64, 128, false, true><<<dim3(256, B), 256, 0, stream>>>(
        out3, 64, 1024, nullptr, w1_4, b1_4, w2_4, b2_4, out4, 512);
}